// Round 8
// baseline (451.411 us; speedup 1.0000x reference)
//
#include <hip/hip_runtime.h>
#include <hip/hip_cooperative_groups.h>

namespace cg = cooperative_groups;

typedef unsigned short u16;
typedef unsigned int u32;
typedef __attribute__((ext_vector_type(8))) short short8;
typedef __attribute__((ext_vector_type(4))) float f32x4;
typedef __attribute__((ext_vector_type(4))) unsigned short ushort4v;
typedef __attribute__((ext_vector_type(4))) float float4v;

// ---------- helpers ----------
__device__ __forceinline__ float bf2f(u16 u) {
    return __uint_as_float(((u32)u) << 16);
}
__device__ __forceinline__ u16 f2bf(float f) {
    u32 u = __float_as_uint(f);
    u += 0x7FFF + ((u >> 16) & 1);   // RNE
    return (u16)(u >> 16);
}
__device__ __forceinline__ short8 cvt8(float4 a, float4 b) {
    short8 r;
    r[0] = (short)f2bf(a.x); r[1] = (short)f2bf(a.y);
    r[2] = (short)f2bf(a.z); r[3] = (short)f2bf(a.w);
    r[4] = (short)f2bf(b.x); r[5] = (short)f2bf(b.y);
    r[6] = (short)f2bf(b.z); r[7] = (short)f2bf(b.w);
    return r;
}
// async global->LDS, 16B per lane; dst wave-uniform (HW adds lane*16)
__device__ __forceinline__ void stage16(const u16* g, u16* l) {
    __builtin_amdgcn_global_load_lds(
        (const __attribute__((address_space(1))) unsigned int*)g,
        (__attribute__((address_space(3))) unsigned int*)l, 16, 0, 0);
}

// ---------- K0: cvt + transpose + row-copy + per-block column partials; Wv cvt in bid>=1024 ----------
__global__ __launch_bounds__(256) void cvt_t(const float* __restrict__ x,
                                             u16* __restrict__ xT,
                                             u16* __restrict__ xb,
                                             float* __restrict__ sp2,
                                             const float* __restrict__ W,
                                             u16* __restrict__ wvb) {
    const int bid = blockIdx.x;
    const int t = threadIdx.x;
    if (bid >= 1024) {   // Wv fp32 -> bf16
        const int i = (bid - 1024) * 256 + t;
        float4v v = ((const float4v*)(W + 524288))[i];
        ushort4v r;
        r[0] = f2bf(v[0]); r[1] = f2bf(v[1]); r[2] = f2bf(v[2]); r[3] = f2bf(v[3]);
        ((ushort4v*)wvb)[i] = r;
        return;
    }
    __shared__ u16 tile[64][136];   // [n][c], pad 8
    const int ct = bid & 3, nt = (bid >> 2) & 127, b = bid >> 9;
    const int r = t >> 2, c0 = (t & 3) * 32;
    const float* src = x + ((size_t)(b * 8192 + nt * 64 + r)) * 512 + ct * 128 + c0;
    short8 r8[4];
#pragma unroll
    for (int j = 0; j < 8; j += 2) {
        float4 v0 = *(const float4*)(src + j * 4);
        float4 v1 = *(const float4*)(src + j * 4 + 4);
        r8[j >> 1] = cvt8(v0, v1);
        *(short8*)(&tile[r][c0 + j * 4]) = r8[j >> 1];
    }
    // row-major bf16 copy
    u16* xbrow = xb + ((size_t)(b * 8192 + nt * 64 + r)) * 512 + ct * 128 + c0;
#pragma unroll
    for (int jj = 0; jj < 4; ++jj) *(short8*)(xbrow + jj * 8) = r8[jj];
    __syncthreads();
    const int c = t >> 1, half = t & 1;
    u16 vals[32];
    float psum = 0.f;
#pragma unroll
    for (int i = 0; i < 32; ++i) {
        vals[i] = tile[half * 32 + i][c];
        psum += bf2f(vals[i]);
    }
    u16* dst = xT + ((size_t)(b * 512 + ct * 128 + c)) * 8192 + nt * 64 + half * 32;
#pragma unroll
    for (int j = 0; j < 4; ++j)
        *(int4*)(dst + j * 8) = *(int4*)(&vals[j * 8]);
    psum += __shfl_xor(psum, 1);
    if ((t & 1) == 0)
        sp2[((size_t)(b * 128 + nt)) * 512 + ct * 128 + c] = psum;   // non-atomic partial
}

// ---------- shared GEMM core: 128x128 tile, BK=32, global_load_lds ----------
template <int STRIDE, int KLEN>
__device__ __forceinline__ void gemm_core(const u16* __restrict__ Ag,
                                          const u16* __restrict__ Bg,
                                          u16* As, u16* Bs, int t,
                                          f32x4 acc[4][4]) {
    const int wv = t >> 6, l = t & 63;
    const int lr = l & 15, lk = (l >> 4) * 8;
    const int wm = (wv >> 1) * 64, wn = (wv & 1) * 64;
    const int srow = l >> 2, scol = (l & 3) * 8;

    u16* Ad0 = As + (wv * 32) * 32;
    u16* Ad1 = As + (wv * 32 + 16) * 32;
    u16* Bd0 = Bs + (wv * 32) * 32;
    u16* Bd1 = Bs + (wv * 32 + 16) * 32;
    const u16* As0 = Ag + (size_t)(wv * 32 + srow) * STRIDE + scol;
    const u16* As1 = Ag + (size_t)(wv * 32 + 16 + srow) * STRIDE + scol;
    const u16* Bs0 = Bg + (size_t)(wv * 32 + srow) * STRIDE + scol;
    const u16* Bs1 = Bg + (size_t)(wv * 32 + 16 + srow) * STRIDE + scol;

    for (int k0 = 0; k0 < KLEN; k0 += 32) {
        stage16(As0 + k0, Ad0);
        stage16(As1 + k0, Ad1);
        stage16(Bs0 + k0, Bd0);
        stage16(Bs1 + k0, Bd1);
        __syncthreads();
        short8 af[4], bfr[4];
#pragma unroll
        for (int mi = 0; mi < 4; ++mi)
            af[mi] = *(const short8*)(As + (wm + mi * 16 + lr) * 32 + lk);
#pragma unroll
        for (int ni = 0; ni < 4; ++ni)
            bfr[ni] = *(const short8*)(Bs + (wn + ni * 16 + lr) * 32 + lk);
#pragma unroll
        for (int mi = 0; mi < 4; ++mi)
#pragma unroll
            for (int ni = 0; ni < 4; ++ni)
                acc[mi][ni] = __builtin_amdgcn_mfma_f32_16x16x32_bf16(
                    af[mi], bfr[ni], acc[mi][ni], 0, 0, 0);
        __syncthreads();
    }
}

// ---------- K1: syrk partials (16 chunks of 512 rows) + ssum reduce ----------
__global__ __launch_bounds__(256) void syrk(const u16* __restrict__ xT,
                                            u16* __restrict__ Spart,
                                            const float* __restrict__ sp2,
                                            float* __restrict__ ssum) {
    const int bid = blockIdx.x, t = threadIdx.x;
    if (bid >= 512) {   // reduce sp2 -> ssum
        const int idx = (bid - 512) * 256 + t;   // [0,1024)
        const int b = idx >> 9, c = idx & 511;
        float a = 0.f;
        for (int j = 0; j < 128; ++j) a += sp2[(size_t)(b * 128 + j) * 512 + c];
        ssum[idx] = a;
        return;
    }
    __shared__ u16 As[128 * 32];
    __shared__ u16 Bs[128 * 32];
    const int nt = bid & 3, mt = (bid >> 2) & 3;
    const int ks = (bid >> 4) & 15, b = bid >> 8;
    const u16* Ag = xT + ((size_t)(b * 512 + mt * 128)) * 8192 + ks * 512;
    const u16* Bg = xT + ((size_t)(b * 512 + nt * 128)) * 8192 + ks * 512;

    f32x4 zz = {0.f, 0.f, 0.f, 0.f};
    f32x4 acc[4][4];
    for (int i = 0; i < 4; ++i)
        for (int j = 0; j < 4; ++j) acc[i][j] = zz;

    gemm_core<8192, 512>(Ag, Bg, As, Bs, t, acc);

    const int l = t & 63, wv = t >> 6;
    const int lr = l & 15;
    const int wm = (wv >> 1) * 64, wn = (wv & 1) * 64;
    u16* out = Spart + ((size_t)(b * 16 + ks)) * 262144;
#pragma unroll
    for (int mi = 0; mi < 4; ++mi)
#pragma unroll
        for (int ni = 0; ni < 4; ++ni) {
            int col = nt * 128 + wn + ni * 16 + lr;
#pragma unroll
            for (int j = 0; j < 4; ++j) {
                int row = mt * 128 + wm + mi * 16 + (l >> 4) * 4 + j;
                out[(size_t)row * 512 + col] = f2bf(acc[mi][ni][j]);
            }
        }
}

// ---------- K2 (cooperative): reduceS -> pgemm -> g2 -> fold -> out_z ----------
__global__ __launch_bounds__(256, 2) void coop_tail(
    const u16* __restrict__ Spart, const float* __restrict__ ssum,
    u16* __restrict__ Sbf, const u16* __restrict__ wvb, u16* __restrict__ Pb,
    const float* __restrict__ W, float* __restrict__ gfull,
    u16* __restrict__ Wgb, const u16* __restrict__ xb, float* __restrict__ z) {
    cg::grid_group grid = cg::this_grid();
    __shared__ __align__(16) char smem[16384];
    u16* As = (u16*)smem;
    u16* Bs = (u16*)(smem + 8192);
    float* gs = (float*)smem;
    const int t = threadIdx.x;
    const int bid = blockIdx.x;
    const int l = t & 63, wvi = t >> 6;
    const int lr = l & 15, lk = (l >> 4) * 8;
    const int wm = (wvi >> 1) * 64, wn = (wvi & 1) * 64;

    // ---- phase 1: reduceS (1024 units over 512 blocks) ----
    for (int u = bid; u < 1024; u += 512) {
        const int b = u >> 9, m = u & 511;
        const float sm = ssum[b * 512 + m] * (1.0f / 8192.0f);
#pragma unroll
        for (int rep = 0; rep < 2; ++rep) {
            const int n = rep * 256 + t;
            float acc = 0.f;
#pragma unroll
            for (int ks = 0; ks < 16; ++ks)
                acc += bf2f(Spart[((size_t)(b * 16 + ks)) * 262144 + (size_t)m * 512 + n]);
            acc -= sm * ssum[b * 512 + n];
            Sbf[(size_t)b * 262144 + (size_t)m * 512 + n] = f2bf(acc);
        }
    }
    __threadfence();
    grid.sync();

    // ---- phase 2: pgemm (32 units) ----
    if (bid < 32) {
        const int nt = bid & 3, mt = (bid >> 2) & 3, b = bid >> 4;
        const u16* Ag = wvb + (size_t)(mt * 128) * 512;
        const u16* Bg = Sbf + (size_t)b * 262144 + (size_t)(nt * 128) * 512;
        f32x4 zz = {0.f, 0.f, 0.f, 0.f};
        f32x4 acc[4][4];
        for (int i = 0; i < 4; ++i)
            for (int j = 0; j < 4; ++j) acc[i][j] = zz;
        gemm_core<512, 512>(Ag, Bg, As, Bs, t, acc);
        u16* out = Pb + (size_t)b * 262144;
#pragma unroll
        for (int mi = 0; mi < 4; ++mi)
#pragma unroll
            for (int ni = 0; ni < 4; ++ni) {
                int col = nt * 128 + wn + ni * 16 + lr;
#pragma unroll
                for (int j = 0; j < 4; ++j) {
                    int row = mt * 128 + wm + mi * 16 + (l >> 4) * 4 + j;
                    out[(size_t)row * 512 + col] = f2bf(acc[mi][ni][j]);
                }
            }
    }
    __threadfence();
    grid.sync();

    // ---- phase 3: g2 (64 units) ----
    if (bid < 64) {
        const int bh = bid >> 2, nt = bid & 3;
        const int b = bh >> 3, h = bh & 7;
        const float* Wk = W + (size_t)(512 + h * 64 + wvi * 16 + lr) * 512;
        const u16* Pr = Pb + (size_t)b * 262144 + (size_t)(h * 64 + nt * 16 + lr) * 512;
        f32x4 acc = {0.f, 0.f, 0.f, 0.f};
        for (int k0 = 0; k0 < 512; k0 += 32) {
            short8 af = cvt8(*(const float4*)(Wk + k0 + lk),
                             *(const float4*)(Wk + k0 + lk + 4));
            short8 bfr = *(const short8*)(Pr + k0 + lk);
            acc = __builtin_amdgcn_mfma_f32_16x16x32_bf16(af, bfr, acc, 0, 0, 0);
        }
#pragma unroll
        for (int j = 0; j < 4; ++j) {
            int d = wvi * 16 + (l >> 4) * 4 + j;
            int e = nt * 16 + lr;
            gfull[(size_t)bh * 4096 + d * 64 + e] = acc[j];
        }
    }
    __threadfence();
    grid.sync();

    // ---- phase 4: fold (128 units) ----
    if (bid < 128) {
        const int bh = bid >> 3, cb = bid & 7;
        const int b = bh >> 3, h = bh & 7;
        for (int i = t; i < 4096; i += 256) gs[i] = gfull[bh * 4096 + i];
        __syncthreads();
        const int c = cb * 64 + (t & 63);
        const int eg = (t >> 6) * 16;
        float acc[16];
#pragma unroll
        for (int j = 0; j < 16; ++j) acc[j] = 0.f;
        for (int d = 0; d < 64; ++d) {
            float w = W[(size_t)(h * 64 + d) * 512 + c];
#pragma unroll
            for (int j = 0; j < 16; ++j) acc[j] += w * gs[d * 64 + eg + j];
        }
#pragma unroll
        for (int j = 0; j < 16; ++j)
            Wgb[(size_t)(b * 512 + h * 64 + eg + j) * 512 + c] = f2bf(acc[j]);
    }
    __threadfence();
    grid.sync();

    // ---- phase 5: out_z (512 units) ----
    {
        const int bx = bid & 127, by = bid >> 7;
        const int m0 = bx * 128;
        const int b = bx >> 6;
        const int n0 = by * 128;
        f32x4 zz = {0.f, 0.f, 0.f, 0.f};
        f32x4 acc[4][4];
        for (int i = 0; i < 4; ++i)
            for (int j = 0; j < 4; ++j) acc[i][j] = zz;
        gemm_core<512, 512>(xb + (size_t)m0 * 512,
                            Wgb + (size_t)b * 262144 + (size_t)n0 * 512, As, Bs, t, acc);
#pragma unroll
        for (int mi = 0; mi < 4; ++mi)
#pragma unroll
            for (int ni = 0; ni < 4; ++ni) {
                int he = n0 + wn + ni * 16 + lr;
                int h = he >> 6, e = he & 63;
#pragma unroll
                for (int j = 0; j < 4; ++j) {
                    int row = m0 + wm + mi * 16 + (l >> 4) * 4 + j;
                    int nidx = row & 8191;
                    z[((size_t)(b * 8 + h) * 8192 + nidx) * 64 + e] =
                        (acc[mi][ni][j] + 0.125f) * 0.0009765625f;
                }
            }
    }
}

extern "C" void kernel_launch(void* const* d_in, const int* in_sizes, int n_in,
                              void* d_out, int out_size, void* d_ws, size_t ws_size,
                              hipStream_t stream) {
    const float* x = (const float*)d_in[0];   // [2,8192,512] fp32
    const float* W = (const float*)d_in[1];   // [1536,512] fp32
    float* z = (float*)d_out;                 // [2,8,8192,64] fp32

    char* ws = (char*)d_ws;
    u16* xT      = (u16*)(ws);                  // 16,777,216 B  [2][512][8192]
    u16* xb      = (u16*)(ws + 16777216);       // 16,777,216 B  [2][8192][512]
    u16* Spart   = (u16*)(ws + 33554432);       // 16,777,216 B  [2][16][512][512]
    u16* Sbf     = (u16*)(ws + 50331648);       //  1,048,576 B  [2][512][512]
    float* sp2   = (float*)(ws + 51380224);     //    524,288 B  [2][128][512]
    float* ssum  = (float*)(ws + 51904512);     //      4,096 B  [2][512]
    u16* wvb     = (u16*)(ws + 51908608);       //    524,288 B  [512][512]
    u16* Pb      = (u16*)(ws + 52432896);       //  1,048,576 B  [2][512][512]
    float* gfull = (float*)(ws + 53481472);     //    262,144 B  [16][64][64]
    u16* Wgb     = (u16*)(ws + 53743616);       //  1,048,576 B  [2][512][512]

    cvt_t<<<1280, 256, 0, stream>>>(x, xT, xb, sp2, W, wvb);
    syrk<<<516, 256, 0, stream>>>(xT, Spart, sp2, ssum);

    void* args[] = {(void*)&Spart, (void*)&ssum, (void*)&Sbf, (void*)&wvb,
                    (void*)&Pb,    (void*)&W,    (void*)&gfull, (void*)&Wgb,
                    (void*)&xb,    (void*)&z};
    hipLaunchCooperativeKernel((void*)coop_tail, dim3(512), dim3(256), args, 0, stream);
}

// Round 9
// 339.732 us; speedup vs baseline: 1.3287x; 1.3287x over previous
//
#include <hip/hip_runtime.h>

typedef unsigned short u16;
typedef unsigned int u32;
typedef __attribute__((ext_vector_type(8))) short short8;
typedef __attribute__((ext_vector_type(4))) float f32x4;
typedef __attribute__((ext_vector_type(4))) unsigned short ushort4v;
typedef __attribute__((ext_vector_type(4))) float float4v;

// ---------- helpers ----------
__device__ __forceinline__ float bf2f(u16 u) {
    return __uint_as_float(((u32)u) << 16);
}
__device__ __forceinline__ u16 f2bf(float f) {
    u32 u = __float_as_uint(f);
    u += 0x7FFF + ((u >> 16) & 1);   // RNE
    return (u16)(u >> 16);
}
__device__ __forceinline__ short8 cvt8(float4 a, float4 b) {
    short8 r;
    r[0] = (short)f2bf(a.x); r[1] = (short)f2bf(a.y);
    r[2] = (short)f2bf(a.z); r[3] = (short)f2bf(a.w);
    r[4] = (short)f2bf(b.x); r[5] = (short)f2bf(b.y);
    r[6] = (short)f2bf(b.z); r[7] = (short)f2bf(b.w);
    return r;
}
// async global->LDS, 16B per lane; dst wave-uniform (HW adds lane*16)
__device__ __forceinline__ void stage16(const u16* g, u16* l) {
    __builtin_amdgcn_global_load_lds(
        (const __attribute__((address_space(1))) unsigned int*)g,
        (__attribute__((address_space(3))) unsigned int*)l, 16, 0, 0);
}
// hand-rolled grid barrier (agent scope). All blocks must be co-resident:
// grid=512, 2 blk/CU capacity guaranteed (16KB LDS, 64 VGPR). Monotone targets.
__device__ __forceinline__ void gsync(int* bar, int target) {
    __syncthreads();
    if (threadIdx.x == 0) {
        __threadfence();   // prior global writes visible device-wide
        __hip_atomic_fetch_add(bar, 1, __ATOMIC_ACQ_REL, __HIP_MEMORY_SCOPE_AGENT);
        while (__hip_atomic_load(bar, __ATOMIC_ACQUIRE, __HIP_MEMORY_SCOPE_AGENT) < target)
            __builtin_amdgcn_s_sleep(8);
    }
    __syncthreads();
}

// ---------- K0: cvt + transpose + row-copy + per-block column partials; Wv cvt in bid>=1024 ----------
__global__ __launch_bounds__(256) void cvt_t(const float* __restrict__ x,
                                             u16* __restrict__ xT,
                                             u16* __restrict__ xb,
                                             float* __restrict__ sp2,
                                             const float* __restrict__ W,
                                             u16* __restrict__ wvb,
                                             int* __restrict__ bar) {
    const int bid = blockIdx.x;
    const int t = threadIdx.x;
    if (bid == 0 && t == 0) *bar = 0;   // reset tail barrier each call (stream-ordered)
    if (bid >= 1024) {   // Wv fp32 -> bf16
        const int i = (bid - 1024) * 256 + t;
        float4v v = ((const float4v*)(W + 524288))[i];
        ushort4v r;
        r[0] = f2bf(v[0]); r[1] = f2bf(v[1]); r[2] = f2bf(v[2]); r[3] = f2bf(v[3]);
        ((ushort4v*)wvb)[i] = r;
        return;
    }
    __shared__ u16 tile[64][136];   // [n][c], pad 8
    const int ct = bid & 3, nt = (bid >> 2) & 127, b = bid >> 9;
    const int r = t >> 2, c0 = (t & 3) * 32;
    const float* src = x + ((size_t)(b * 8192 + nt * 64 + r)) * 512 + ct * 128 + c0;
    short8 r8[4];
#pragma unroll
    for (int j = 0; j < 8; j += 2) {
        float4 v0 = *(const float4*)(src + j * 4);
        float4 v1 = *(const float4*)(src + j * 4 + 4);
        r8[j >> 1] = cvt8(v0, v1);
        *(short8*)(&tile[r][c0 + j * 4]) = r8[j >> 1];
    }
    // row-major bf16 copy
    u16* xbrow = xb + ((size_t)(b * 8192 + nt * 64 + r)) * 512 + ct * 128 + c0;
#pragma unroll
    for (int jj = 0; jj < 4; ++jj) *(short8*)(xbrow + jj * 8) = r8[jj];
    __syncthreads();
    const int c = t >> 1, half = t & 1;
    u16 vals[32];
    float psum = 0.f;
#pragma unroll
    for (int i = 0; i < 32; ++i) {
        vals[i] = tile[half * 32 + i][c];
        psum += bf2f(vals[i]);
    }
    u16* dst = xT + ((size_t)(b * 512 + ct * 128 + c)) * 8192 + nt * 64 + half * 32;
#pragma unroll
    for (int j = 0; j < 4; ++j)
        *(int4*)(dst + j * 8) = *(int4*)(&vals[j * 8]);
    psum += __shfl_xor(psum, 1);
    if ((t & 1) == 0)
        sp2[((size_t)(b * 128 + nt)) * 512 + ct * 128 + c] = psum;   // non-atomic partial
}

// ---------- shared GEMM core: 128x128 tile, BK=32, global_load_lds ----------
template <int STRIDE, int KLEN>
__device__ __forceinline__ void gemm_core(const u16* __restrict__ Ag,
                                          const u16* __restrict__ Bg,
                                          u16* As, u16* Bs, int t,
                                          f32x4 acc[4][4]) {
    const int wv = t >> 6, l = t & 63;
    const int lr = l & 15, lk = (l >> 4) * 8;
    const int wm = (wv >> 1) * 64, wn = (wv & 1) * 64;
    const int srow = l >> 2, scol = (l & 3) * 8;

    u16* Ad0 = As + (wv * 32) * 32;
    u16* Ad1 = As + (wv * 32 + 16) * 32;
    u16* Bd0 = Bs + (wv * 32) * 32;
    u16* Bd1 = Bs + (wv * 32 + 16) * 32;
    const u16* As0 = Ag + (size_t)(wv * 32 + srow) * STRIDE + scol;
    const u16* As1 = Ag + (size_t)(wv * 32 + 16 + srow) * STRIDE + scol;
    const u16* Bs0 = Bg + (size_t)(wv * 32 + srow) * STRIDE + scol;
    const u16* Bs1 = Bg + (size_t)(wv * 32 + 16 + srow) * STRIDE + scol;

    for (int k0 = 0; k0 < KLEN; k0 += 32) {
        stage16(As0 + k0, Ad0);
        stage16(As1 + k0, Ad1);
        stage16(Bs0 + k0, Bd0);
        stage16(Bs1 + k0, Bd1);
        __syncthreads();
        short8 af[4], bfr[4];
#pragma unroll
        for (int mi = 0; mi < 4; ++mi)
            af[mi] = *(const short8*)(As + (wm + mi * 16 + lr) * 32 + lk);
#pragma unroll
        for (int ni = 0; ni < 4; ++ni)
            bfr[ni] = *(const short8*)(Bs + (wn + ni * 16 + lr) * 32 + lk);
#pragma unroll
        for (int mi = 0; mi < 4; ++mi)
#pragma unroll
            for (int ni = 0; ni < 4; ++ni)
                acc[mi][ni] = __builtin_amdgcn_mfma_f32_16x16x32_bf16(
                    af[mi], bfr[ni], acc[mi][ni], 0, 0, 0);
        __syncthreads();
    }
}

// ---------- K1: syrk partials (16 chunks of 512 rows) + ssum reduce ----------
__global__ __launch_bounds__(256) void syrk(const u16* __restrict__ xT,
                                            u16* __restrict__ Spart,
                                            const float* __restrict__ sp2,
                                            float* __restrict__ ssum) {
    const int bid = blockIdx.x, t = threadIdx.x;
    if (bid >= 512) {   // reduce sp2 -> ssum
        const int idx = (bid - 512) * 256 + t;   // [0,1024)
        const int b = idx >> 9, c = idx & 511;
        float a = 0.f;
        for (int j = 0; j < 128; ++j) a += sp2[(size_t)(b * 128 + j) * 512 + c];
        ssum[idx] = a;
        return;
    }
    __shared__ u16 As[128 * 32];
    __shared__ u16 Bs[128 * 32];
    const int nt = bid & 3, mt = (bid >> 2) & 3;
    const int ks = (bid >> 4) & 15, b = bid >> 8;
    const u16* Ag = xT + ((size_t)(b * 512 + mt * 128)) * 8192 + ks * 512;
    const u16* Bg = xT + ((size_t)(b * 512 + nt * 128)) * 8192 + ks * 512;

    f32x4 zz = {0.f, 0.f, 0.f, 0.f};
    f32x4 acc[4][4];
    for (int i = 0; i < 4; ++i)
        for (int j = 0; j < 4; ++j) acc[i][j] = zz;

    gemm_core<8192, 512>(Ag, Bg, As, Bs, t, acc);

    const int l = t & 63, wv = t >> 6;
    const int lr = l & 15;
    const int wm = (wv >> 1) * 64, wn = (wv & 1) * 64;
    u16* out = Spart + ((size_t)(b * 16 + ks)) * 262144;
#pragma unroll
    for (int mi = 0; mi < 4; ++mi)
#pragma unroll
        for (int ni = 0; ni < 4; ++ni) {
            int col = nt * 128 + wn + ni * 16 + lr;
#pragma unroll
            for (int j = 0; j < 4; ++j) {
                int row = mt * 128 + wm + mi * 16 + (l >> 4) * 4 + j;
                out[(size_t)row * 512 + col] = f2bf(acc[mi][ni][j]);
            }
        }
}

// ---------- K2 (fused tail, hand-rolled grid barrier): reduceS -> pgemm -> g2 -> fold -> out_z ----------
__global__ __launch_bounds__(256, 2) void fused_tail(
    const u16* __restrict__ Spart, const float* __restrict__ ssum,
    u16* __restrict__ Sbf, const u16* __restrict__ wvb, u16* __restrict__ Pb,
    const float* __restrict__ W, float* __restrict__ gfull,
    u16* __restrict__ Wgb, const u16* __restrict__ xb, float* __restrict__ z,
    int* __restrict__ bar) {
    __shared__ __align__(16) char smem[16384];
    u16* As = (u16*)smem;
    u16* Bs = (u16*)(smem + 8192);
    float* gs = (float*)smem;
    const int t = threadIdx.x;
    const int bid = blockIdx.x;
    const int l = t & 63, wvi = t >> 6;
    const int lr = l & 15, lk = (l >> 4) * 8;
    const int wm = (wvi >> 1) * 64, wn = (wvi & 1) * 64;

    // ---- phase 1: reduceS (1024 units over 512 blocks) ----
    for (int u = bid; u < 1024; u += 512) {
        const int b = u >> 9, m = u & 511;
        const float sm = ssum[b * 512 + m] * (1.0f / 8192.0f);
#pragma unroll
        for (int rep = 0; rep < 2; ++rep) {
            const int n = rep * 256 + t;
            float acc = 0.f;
#pragma unroll
            for (int ks = 0; ks < 16; ++ks)
                acc += bf2f(Spart[((size_t)(b * 16 + ks)) * 262144 + (size_t)m * 512 + n]);
            acc -= sm * ssum[b * 512 + n];
            Sbf[(size_t)b * 262144 + (size_t)m * 512 + n] = f2bf(acc);
        }
    }
    gsync(bar, 512);

    // ---- phase 2: pgemm (32 units) ----
    if (bid < 32) {
        const int nt = bid & 3, mt = (bid >> 2) & 3, b = bid >> 4;
        const u16* Ag = wvb + (size_t)(mt * 128) * 512;
        const u16* Bg = Sbf + (size_t)b * 262144 + (size_t)(nt * 128) * 512;
        f32x4 zz = {0.f, 0.f, 0.f, 0.f};
        f32x4 acc[4][4];
        for (int i = 0; i < 4; ++i)
            for (int j = 0; j < 4; ++j) acc[i][j] = zz;
        gemm_core<512, 512>(Ag, Bg, As, Bs, t, acc);
        u16* out = Pb + (size_t)b * 262144;
#pragma unroll
        for (int mi = 0; mi < 4; ++mi)
#pragma unroll
            for (int ni = 0; ni < 4; ++ni) {
                int col = nt * 128 + wn + ni * 16 + lr;
#pragma unroll
                for (int j = 0; j < 4; ++j) {
                    int row = mt * 128 + wm + mi * 16 + (l >> 4) * 4 + j;
                    out[(size_t)row * 512 + col] = f2bf(acc[mi][ni][j]);
                }
            }
    }
    gsync(bar, 1024);

    // ---- phase 3: g2 (64 units) ----
    if (bid < 64) {
        const int bh = bid >> 2, nt = bid & 3;
        const int b = bh >> 3, h = bh & 7;
        const float* Wk = W + (size_t)(512 + h * 64 + wvi * 16 + lr) * 512;
        const u16* Pr = Pb + (size_t)b * 262144 + (size_t)(h * 64 + nt * 16 + lr) * 512;
        f32x4 acc = {0.f, 0.f, 0.f, 0.f};
        for (int k0 = 0; k0 < 512; k0 += 32) {
            short8 af = cvt8(*(const float4*)(Wk + k0 + lk),
                             *(const float4*)(Wk + k0 + lk + 4));
            short8 bfr = *(const short8*)(Pr + k0 + lk);
            acc = __builtin_amdgcn_mfma_f32_16x16x32_bf16(af, bfr, acc, 0, 0, 0);
        }
#pragma unroll
        for (int j = 0; j < 4; ++j) {
            int d = wvi * 16 + (l >> 4) * 4 + j;
            int e = nt * 16 + lr;
            gfull[(size_t)bh * 4096 + d * 64 + e] = acc[j];
        }
    }
    gsync(bar, 1536);

    // ---- phase 4: fold (128 units) ----
    if (bid < 128) {
        const int bh = bid >> 3, cb = bid & 7;
        const int b = bh >> 3, h = bh & 7;
        for (int i = t; i < 4096; i += 256) gs[i] = gfull[bh * 4096 + i];
        __syncthreads();
        const int c = cb * 64 + (t & 63);
        const int eg = (t >> 6) * 16;
        float acc[16];
#pragma unroll
        for (int j = 0; j < 16; ++j) acc[j] = 0.f;
        for (int d = 0; d < 64; ++d) {
            float w = W[(size_t)(h * 64 + d) * 512 + c];
#pragma unroll
            for (int j = 0; j < 16; ++j) acc[j] += w * gs[d * 64 + eg + j];
        }
#pragma unroll
        for (int j = 0; j < 16; ++j)
            Wgb[(size_t)(b * 512 + h * 64 + eg + j) * 512 + c] = f2bf(acc[j]);
    }
    gsync(bar, 2048);

    // ---- phase 5: out_z (512 units) ----
    {
        const int bx = bid & 127, by = bid >> 7;
        const int m0 = bx * 128;
        const int b = bx >> 6;
        const int n0 = by * 128;
        f32x4 zz = {0.f, 0.f, 0.f, 0.f};
        f32x4 acc[4][4];
        for (int i = 0; i < 4; ++i)
            for (int j = 0; j < 4; ++j) acc[i][j] = zz;
        gemm_core<512, 512>(xb + (size_t)m0 * 512,
                            Wgb + (size_t)b * 262144 + (size_t)n0 * 512, As, Bs, t, acc);
#pragma unroll
        for (int mi = 0; mi < 4; ++mi)
#pragma unroll
            for (int ni = 0; ni < 4; ++ni) {
                int he = n0 + wn + ni * 16 + lr;
                int h = he >> 6, e = he & 63;
#pragma unroll
                for (int j = 0; j < 4; ++j) {
                    int row = m0 + wm + mi * 16 + (l >> 4) * 4 + j;
                    int nidx = row & 8191;
                    z[((size_t)(b * 8 + h) * 8192 + nidx) * 64 + e] =
                        (acc[mi][ni][j] + 0.125f) * 0.0009765625f;
                }
            }
    }
}

extern "C" void kernel_launch(void* const* d_in, const int* in_sizes, int n_in,
                              void* d_out, int out_size, void* d_ws, size_t ws_size,
                              hipStream_t stream) {
    const float* x = (const float*)d_in[0];   // [2,8192,512] fp32
    const float* W = (const float*)d_in[1];   // [1536,512] fp32
    float* z = (float*)d_out;                 // [2,8,8192,64] fp32

    char* ws = (char*)d_ws;
    u16* xT      = (u16*)(ws);                  // 16,777,216 B  [2][512][8192]
    u16* xb      = (u16*)(ws + 16777216);       // 16,777,216 B  [2][8192][512]
    u16* Spart   = (u16*)(ws + 33554432);       // 16,777,216 B  [2][16][512][512]
    u16* Sbf     = (u16*)(ws + 50331648);       //  1,048,576 B  [2][512][512]
    float* sp2   = (float*)(ws + 51380224);     //    524,288 B  [2][128][512]
    float* ssum  = (float*)(ws + 51904512);     //      4,096 B  [2][512]
    u16* wvb     = (u16*)(ws + 51908608);       //    524,288 B  [512][512]
    u16* Pb      = (u16*)(ws + 52432896);       //  1,048,576 B  [2][512][512]
    float* gfull = (float*)(ws + 53481472);     //    262,144 B  [16][64][64]
    u16* Wgb     = (u16*)(ws + 53743616);       //  1,048,576 B  [2][512][512]
    int* bar     = (int*)(ws + 54796288);       //         64 B  (own cacheline)

    cvt_t<<<1280, 256, 0, stream>>>(x, xT, xb, sp2, W, wvb, bar);
    syrk<<<516, 256, 0, stream>>>(xT, Spart, sp2, ssum);
    fused_tail<<<512, 256, 0, stream>>>(Spart, ssum, Sbf, wvb, Pb, W, gfull,
                                        Wgb, xb, z, bar);
}

// Round 10
// 85.336 us; speedup vs baseline: 5.2898x; 3.9811x over previous
//
#include <hip/hip_runtime.h>

typedef unsigned short u16;
typedef unsigned int u32;
typedef __attribute__((ext_vector_type(8))) short short8;
typedef __attribute__((ext_vector_type(4))) float f32x4;
typedef __attribute__((ext_vector_type(4))) unsigned short ushort4v;
typedef __attribute__((ext_vector_type(4))) float float4v;

// ---------- helpers ----------
__device__ __forceinline__ float bf2f(u16 u) {
    return __uint_as_float(((u32)u) << 16);
}
__device__ __forceinline__ u16 f2bf(float f) {
    u32 u = __float_as_uint(f);
    u += 0x7FFF + ((u >> 16) & 1);   // RNE
    return (u16)(u >> 16);
}
__device__ __forceinline__ short8 cvt8(float4 a, float4 b) {
    short8 r;
    r[0] = (short)f2bf(a.x); r[1] = (short)f2bf(a.y);
    r[2] = (short)f2bf(a.z); r[3] = (short)f2bf(a.w);
    r[4] = (short)f2bf(b.x); r[5] = (short)f2bf(b.y);
    r[6] = (short)f2bf(b.z); r[7] = (short)f2bf(b.w);
    return r;
}
// async global->LDS, 16B per lane; dst wave-uniform (HW adds lane*16)
__device__ __forceinline__ void stage16(const u16* g, u16* l) {
    __builtin_amdgcn_global_load_lds(
        (const __attribute__((address_space(1))) unsigned int*)g,
        (__attribute__((address_space(3))) unsigned int*)l, 16, 0, 0);
}

// ---------- K0: cvt+transpose+row-copy+colsum partials | Wv cvt | U_h = Wq_h^T Wk_h ----------
__global__ __launch_bounds__(256) void cvt_t(const float* __restrict__ x,
                                             u16* __restrict__ xT,
                                             u16* __restrict__ xb,
                                             float* __restrict__ sp2,
                                             const float* __restrict__ W,
                                             u16* __restrict__ wvb,
                                             u16* __restrict__ Ub) {
    __shared__ __align__(16) char smem[36864];
    const int bid = blockIdx.x;
    const int t = threadIdx.x;
    if (bid >= 1280) {   // U-compute: 128 blocks = h(8) x mt(4) x nt(4), K=64
        const int u = bid - 1280;
        const int h = u >> 4, mt = (u >> 2) & 3, ntt = u & 3;
        u16 (*At)[72] = (u16(*)[72])smem;              // [c1][d] K-major, pad 72
        u16 (*Bt)[72] = (u16(*)[72])(smem + 18432);    // [c2][d]
        const int d = t >> 2, cg = (t & 3) * 32;
        const float* wq = W + (size_t)(h * 64 + d) * 512 + mt * 128 + cg;
        const float* wk = W + (size_t)(512 + h * 64 + d) * 512 + ntt * 128 + cg;
#pragma unroll
        for (int j = 0; j < 32; j += 4) {
            float4 a = *(const float4*)(wq + j);
            float4 kk = *(const float4*)(wk + j);
            At[cg + j + 0][d] = f2bf(a.x); At[cg + j + 1][d] = f2bf(a.y);
            At[cg + j + 2][d] = f2bf(a.z); At[cg + j + 3][d] = f2bf(a.w);
            Bt[cg + j + 0][d] = f2bf(kk.x); Bt[cg + j + 1][d] = f2bf(kk.y);
            Bt[cg + j + 2][d] = f2bf(kk.z); Bt[cg + j + 3][d] = f2bf(kk.w);
        }
        __syncthreads();
        const int l = t & 63, wv = t >> 6;
        const int lr = l & 15, lk = (l >> 4) * 8;
        const int wm = (wv >> 1) * 64, wn = (wv & 1) * 64;
        f32x4 zz = {0.f, 0.f, 0.f, 0.f};
        f32x4 acc[4][4];
        for (int i = 0; i < 4; ++i)
            for (int j = 0; j < 4; ++j) acc[i][j] = zz;
#pragma unroll
        for (int k0 = 0; k0 < 64; k0 += 32) {
            short8 af[4], bfr[4];
#pragma unroll
            for (int mi = 0; mi < 4; ++mi)
                af[mi] = *(const short8*)(&At[wm + mi * 16 + lr][k0 + lk]);
#pragma unroll
            for (int ni = 0; ni < 4; ++ni)
                bfr[ni] = *(const short8*)(&Bt[wn + ni * 16 + lr][k0 + lk]);
#pragma unroll
            for (int mi = 0; mi < 4; ++mi)
#pragma unroll
                for (int ni = 0; ni < 4; ++ni)
                    acc[mi][ni] = __builtin_amdgcn_mfma_f32_16x16x32_bf16(
                        af[mi], bfr[ni], acc[mi][ni], 0, 0, 0);
        }
#pragma unroll
        for (int mi = 0; mi < 4; ++mi)
#pragma unroll
            for (int ni = 0; ni < 4; ++ni) {
                int col = ntt * 128 + wn + ni * 16 + lr;
#pragma unroll
                for (int j = 0; j < 4; ++j) {
                    int row = mt * 128 + wm + mi * 16 + (l >> 4) * 4 + j;
                    Ub[((size_t)(h * 512 + row)) * 512 + col] = f2bf(acc[mi][ni][j]);
                }
            }
        return;
    }
    if (bid >= 1024) {   // Wv fp32 -> bf16
        const int i = (bid - 1024) * 256 + t;
        float4v v = ((const float4v*)(W + 524288))[i];
        ushort4v r;
        r[0] = f2bf(v[0]); r[1] = f2bf(v[1]); r[2] = f2bf(v[2]); r[3] = f2bf(v[3]);
        ((ushort4v*)wvb)[i] = r;
        return;
    }
    u16 (*tile)[136] = (u16(*)[136])smem;   // [n][c], pad 8
    const int ct = bid & 3, nt = (bid >> 2) & 127, b = bid >> 9;
    const int r = t >> 2, c0 = (t & 3) * 32;
    const float* src = x + ((size_t)(b * 8192 + nt * 64 + r)) * 512 + ct * 128 + c0;
    short8 r8[4];
#pragma unroll
    for (int j = 0; j < 8; j += 2) {
        float4 v0 = *(const float4*)(src + j * 4);
        float4 v1 = *(const float4*)(src + j * 4 + 4);
        r8[j >> 1] = cvt8(v0, v1);
        *(short8*)(&tile[r][c0 + j * 4]) = r8[j >> 1];
    }
    // row-major bf16 copy
    u16* xbrow = xb + ((size_t)(b * 8192 + nt * 64 + r)) * 512 + ct * 128 + c0;
#pragma unroll
    for (int jj = 0; jj < 4; ++jj) *(short8*)(xbrow + jj * 8) = r8[jj];
    __syncthreads();
    const int c = t >> 1, half = t & 1;
    u16 vals[32];
    float psum = 0.f;
#pragma unroll
    for (int i = 0; i < 32; ++i) {
        vals[i] = tile[half * 32 + i][c];
        psum += bf2f(vals[i]);
    }
    u16* dst = xT + ((size_t)(b * 512 + ct * 128 + c)) * 8192 + nt * 64 + half * 32;
#pragma unroll
    for (int j = 0; j < 4; ++j)
        *(int4*)(dst + j * 8) = *(int4*)(&vals[j * 8]);
    psum += __shfl_xor(psum, 1);
    if ((t & 1) == 0)
        sp2[((size_t)(b * 128 + nt)) * 512 + ct * 128 + c] = psum;   // non-atomic partial
}

// ---------- shared GEMM core: 128x128 tile, BK=32, global_load_lds ----------
template <int STRIDE, int KLEN>
__device__ __forceinline__ void gemm_core(const u16* __restrict__ Ag,
                                          const u16* __restrict__ Bg,
                                          u16* As, u16* Bs, int t,
                                          f32x4 acc[4][4]) {
    const int wv = t >> 6, l = t & 63;
    const int lr = l & 15, lk = (l >> 4) * 8;
    const int wm = (wv >> 1) * 64, wn = (wv & 1) * 64;
    const int srow = l >> 2, scol = (l & 3) * 8;

    u16* Ad0 = As + (wv * 32) * 32;
    u16* Ad1 = As + (wv * 32 + 16) * 32;
    u16* Bd0 = Bs + (wv * 32) * 32;
    u16* Bd1 = Bs + (wv * 32 + 16) * 32;
    const u16* As0 = Ag + (size_t)(wv * 32 + srow) * STRIDE + scol;
    const u16* As1 = Ag + (size_t)(wv * 32 + 16 + srow) * STRIDE + scol;
    const u16* Bs0 = Bg + (size_t)(wv * 32 + srow) * STRIDE + scol;
    const u16* Bs1 = Bg + (size_t)(wv * 32 + 16 + srow) * STRIDE + scol;

    for (int k0 = 0; k0 < KLEN; k0 += 32) {
        stage16(As0 + k0, Ad0);
        stage16(As1 + k0, Ad1);
        stage16(Bs0 + k0, Bd0);
        stage16(Bs1 + k0, Bd1);
        __syncthreads();
        short8 af[4], bfr[4];
#pragma unroll
        for (int mi = 0; mi < 4; ++mi)
            af[mi] = *(const short8*)(As + (wm + mi * 16 + lr) * 32 + lk);
#pragma unroll
        for (int ni = 0; ni < 4; ++ni)
            bfr[ni] = *(const short8*)(Bs + (wn + ni * 16 + lr) * 32 + lk);
#pragma unroll
        for (int mi = 0; mi < 4; ++mi)
#pragma unroll
            for (int ni = 0; ni < 4; ++ni)
                acc[mi][ni] = __builtin_amdgcn_mfma_f32_16x16x32_bf16(
                    af[mi], bfr[ni], acc[mi][ni], 0, 0, 0);
        __syncthreads();
    }
}

// ---------- K1: syrk partials (16 chunks of 512 rows) + ssum reduce ----------
__global__ __launch_bounds__(256) void syrk(const u16* __restrict__ xT,
                                            u16* __restrict__ Spart,
                                            const float* __restrict__ sp2,
                                            float* __restrict__ ssum) {
    const int bid = blockIdx.x, t = threadIdx.x;
    if (bid >= 512) {   // reduce sp2 -> ssum
        const int idx = (bid - 512) * 256 + t;   // [0,1024)
        const int b = idx >> 9, c = idx & 511;
        float a = 0.f;
        for (int j = 0; j < 128; ++j) a += sp2[(size_t)(b * 128 + j) * 512 + c];
        ssum[idx] = a;
        return;
    }
    __shared__ u16 As[128 * 32];
    __shared__ u16 Bs[128 * 32];
    const int nt = bid & 3, mt = (bid >> 2) & 3;
    const int ks = (bid >> 4) & 15, b = bid >> 8;
    const u16* Ag = xT + ((size_t)(b * 512 + mt * 128)) * 8192 + ks * 512;
    const u16* Bg = xT + ((size_t)(b * 512 + nt * 128)) * 8192 + ks * 512;

    f32x4 zz = {0.f, 0.f, 0.f, 0.f};
    f32x4 acc[4][4];
    for (int i = 0; i < 4; ++i)
        for (int j = 0; j < 4; ++j) acc[i][j] = zz;

    gemm_core<8192, 512>(Ag, Bg, As, Bs, t, acc);

    const int l = t & 63, wv = t >> 6;
    const int lr = l & 15;
    const int wm = (wv >> 1) * 64, wn = (wv & 1) * 64;
    u16* out = Spart + ((size_t)(b * 16 + ks)) * 262144;
#pragma unroll
    for (int mi = 0; mi < 4; ++mi)
#pragma unroll
        for (int ni = 0; ni < 4; ++ni) {
            int col = nt * 128 + wn + ni * 16 + lr;
#pragma unroll
            for (int j = 0; j < 4; ++j) {
                int row = mt * 128 + wm + mi * 16 + (l >> 4) * 4 + j;
                out[(size_t)row * 512 + col] = f2bf(acc[mi][ni][j]);
            }
        }
}

// ---------- K2: reduce partials + centering -> S' bf16 [2][512][512] ----------
__global__ __launch_bounds__(256) void reduceS(const u16* __restrict__ Spart,
                                               const float* __restrict__ s,
                                               u16* __restrict__ Sbf) {
    const int b = blockIdx.x >> 9, m = blockIdx.x & 511;
    const int t = threadIdx.x;
    const float sm = s[b * 512 + m] * (1.0f / 8192.0f);
#pragma unroll
    for (int rep = 0; rep < 2; ++rep) {
        const int n = rep * 256 + t;
        float acc = 0.f;
#pragma unroll
        for (int ks = 0; ks < 16; ++ks)
            acc += bf2f(Spart[((size_t)(b * 16 + ks)) * 262144 + (size_t)m * 512 + n]);
        acc -= sm * s[b * 512 + n];
        Sbf[(size_t)b * 262144 + (size_t)m * 512 + n] = f2bf(acc);
    }
}

// ---------- K3: P = Wv * S'_b, write bf16 ----------
__global__ __launch_bounds__(256) void pgemm(const u16* __restrict__ wvb,
                                             const u16* __restrict__ Sbf,
                                             u16* __restrict__ Pb) {
    __shared__ u16 As[128 * 32];
    __shared__ u16 Bs[128 * 32];
    const int t = threadIdx.x;
    const int nt = blockIdx.x & 3, mt = (blockIdx.x >> 2) & 3, b = blockIdx.x >> 4;
    const u16* Ag = wvb + (size_t)(mt * 128) * 512;
    const u16* Bg = Sbf + (size_t)b * 262144 + (size_t)(nt * 128) * 512;

    f32x4 zz = {0.f, 0.f, 0.f, 0.f};
    f32x4 acc[4][4];
    for (int i = 0; i < 4; ++i)
        for (int j = 0; j < 4; ++j) acc[i][j] = zz;

    gemm_core<512, 512>(Ag, Bg, As, Bs, t, acc);

    const int l = t & 63, wv = t >> 6;
    const int lr = l & 15;
    const int wm = (wv >> 1) * 64, wn = (wv & 1) * 64;
    u16* out = Pb + (size_t)b * 262144;
#pragma unroll
    for (int mi = 0; mi < 4; ++mi)
#pragma unroll
        for (int ni = 0; ni < 4; ++ni) {
            int col = nt * 128 + wn + ni * 16 + lr;
#pragma unroll
            for (int j = 0; j < 4; ++j) {
                int row = mt * 128 + wm + mi * 16 + (l >> 4) * 4 + j;
                out[(size_t)row * 512 + col] = f2bf(acc[mi][ni][j]);
            }
        }
}

// ---------- K4: Wg_bh = P_bh (64x512) x U_h^T -> Wgb rows he, cols c1 ----------
// 64 blocks = 16 bh x 4 c1-tiles; 64x128 tile, waves 2Mx2N
__global__ __launch_bounds__(256) void wgg(const u16* __restrict__ Ub,
                                           const u16* __restrict__ Pb,
                                           u16* __restrict__ Wgb) {
    __shared__ u16 As[64 * 32];
    __shared__ u16 Bs[128 * 32];
    const int bh = blockIdx.x >> 2, ct = blockIdx.x & 3;
    const int b = bh >> 3, h = bh & 7;
    const int t = threadIdx.x, wv = t >> 6, l = t & 63;
    const int lr = l & 15, lk = (l >> 4) * 8;
    const int wm = (wv >> 1) * 32, wn = (wv & 1) * 64;
    const int srow = l >> 2, scol = (l & 3) * 8;

    const u16* Ag = Pb + (size_t)b * 262144 + (size_t)(h * 64) * 512;     // P rows he
    const u16* Bg = Ub + (size_t)(h * 512 + ct * 128) * 512;              // U rows c1
    u16* Ad = As + (wv * 16) * 32;
    u16* Bd0 = Bs + (wv * 32) * 32;
    u16* Bd1 = Bs + (wv * 32 + 16) * 32;
    const u16* As0 = Ag + (size_t)(wv * 16 + srow) * 512 + scol;
    const u16* Bs0 = Bg + (size_t)(wv * 32 + srow) * 512 + scol;
    const u16* Bs1 = Bg + (size_t)(wv * 32 + 16 + srow) * 512 + scol;

    f32x4 zz = {0.f, 0.f, 0.f, 0.f};
    f32x4 acc[2][4];
    for (int i = 0; i < 2; ++i)
        for (int j = 0; j < 4; ++j) acc[i][j] = zz;

    for (int k0 = 0; k0 < 512; k0 += 32) {
        stage16(As0 + k0, Ad);
        stage16(Bs0 + k0, Bd0);
        stage16(Bs1 + k0, Bd1);
        __syncthreads();
        short8 af[2], bfr[4];
#pragma unroll
        for (int mi = 0; mi < 2; ++mi)
            af[mi] = *(const short8*)(As + (wm + mi * 16 + lr) * 32 + lk);
#pragma unroll
        for (int ni = 0; ni < 4; ++ni)
            bfr[ni] = *(const short8*)(Bs + (wn + ni * 16 + lr) * 32 + lk);
#pragma unroll
        for (int mi = 0; mi < 2; ++mi)
#pragma unroll
            for (int ni = 0; ni < 4; ++ni)
                acc[mi][ni] = __builtin_amdgcn_mfma_f32_16x16x32_bf16(
                    af[mi], bfr[ni], acc[mi][ni], 0, 0, 0);
        __syncthreads();
    }
#pragma unroll
    for (int mi = 0; mi < 2; ++mi)
#pragma unroll
        for (int ni = 0; ni < 4; ++ni) {
            int col = ct * 128 + wn + ni * 16 + lr;
#pragma unroll
            for (int j = 0; j < 4; ++j) {
                int row = wm + mi * 16 + (l >> 4) * 4 + j;   // he in [0,64)
                Wgb[((size_t)(b * 512 + h * 64 + row)) * 512 + col] = f2bf(acc[mi][ni][j]);
            }
        }
}

// ---------- K5: z = scale/1024 + (x @ Wg)/1024, both operands bf16 staged ----------
__global__ __launch_bounds__(256) void out_z(const u16* __restrict__ xb,
                                             const u16* __restrict__ Wgb,
                                             float* __restrict__ z) {
    __shared__ u16 As[128 * 32];
    __shared__ u16 Bs[128 * 32];
    const int t = threadIdx.x;
    const int m0 = blockIdx.x * 128;
    const int b = blockIdx.x >> 6;
    const int n0 = blockIdx.y * 128;

    f32x4 zz = {0.f, 0.f, 0.f, 0.f};
    f32x4 acc[4][4];
    for (int i = 0; i < 4; ++i)
        for (int j = 0; j < 4; ++j) acc[i][j] = zz;

    gemm_core<512, 512>(xb + (size_t)m0 * 512,
                        Wgb + (size_t)b * 262144 + (size_t)n0 * 512, As, Bs, t, acc);

    const int l = t & 63, wv = t >> 6;
    const int lr = l & 15;
    const int wm = (wv >> 1) * 64, wn = (wv & 1) * 64;
#pragma unroll
    for (int mi = 0; mi < 4; ++mi)
#pragma unroll
        for (int ni = 0; ni < 4; ++ni) {
            int he = n0 + wn + ni * 16 + lr;
            int h = he >> 6, e = he & 63;
#pragma unroll
            for (int j = 0; j < 4; ++j) {
                int row = m0 + wm + mi * 16 + (l >> 4) * 4 + j;
                int nidx = row & 8191;
                z[((size_t)(b * 8 + h) * 8192 + nidx) * 64 + e] =
                    (acc[mi][ni][j] + 0.125f) * 0.0009765625f;
            }
        }
}

extern "C" void kernel_launch(void* const* d_in, const int* in_sizes, int n_in,
                              void* d_out, int out_size, void* d_ws, size_t ws_size,
                              hipStream_t stream) {
    const float* x = (const float*)d_in[0];   // [2,8192,512] fp32
    const float* W = (const float*)d_in[1];   // [1536,512] fp32
    float* z = (float*)d_out;                 // [2,8,8192,64] fp32

    char* ws = (char*)d_ws;
    u16* xT      = (u16*)(ws);                  // 16,777,216 B  [2][512][8192]
    u16* xb      = (u16*)(ws + 16777216);       // 16,777,216 B  [2][8192][512]
    u16* Spart   = (u16*)(ws + 33554432);       // 16,777,216 B  [2][16][512][512]
    u16* Sbf     = (u16*)(ws + 50331648);       //  1,048,576 B  [2][512][512]
    float* sp2   = (float*)(ws + 51380224);     //    524,288 B  [2][128][512]
    float* ssum  = (float*)(ws + 51904512);     //      4,096 B  [2][512]
    u16* wvb     = (u16*)(ws + 51908608);       //    524,288 B  [512][512]
    u16* Pb      = (u16*)(ws + 52432896);       //  1,048,576 B  [2][512][512]
    u16* Ub      = (u16*)(ws + 53481472);       //  4,194,304 B  [8][512][512]
    u16* Wgb     = (u16*)(ws + 57675776);       //  1,048,576 B  [2][512][512]

    cvt_t<<<1408, 256, 0, stream>>>(x, xT, xb, sp2, W, wvb, Ub);
    syrk<<<516, 256, 0, stream>>>(xT, Spart, sp2, ssum);
    reduceS<<<1024, 256, 0, stream>>>(Spart, ssum, Sbf);
    pgemm<<<32, 256, 0, stream>>>(wvb, Sbf, Pb);
    wgg<<<64, 256, 0, stream>>>(Ub, Pb, Wgb);
    out_z<<<dim3(128, 4), 256, 0, stream>>>(xb, Wgb, z);
}